// Round 1
// baseline (3391.843 us; speedup 1.0000x reference)
//
#include <hip/hip_runtime.h>

// SpectralConv4d: out = irfftn( corner_mul(rfftn(x), W) )
// x: [2,32,32,32,32,32] f32, W: [8,32,32,12,12,12,12,2] f32
// Only modes k1,k2,k3 in {0..11}u{20..31} (24 each) and k4 in {0..11} matter.
// 5 kernels: fwd(d3,d4) -> fwd(d2,d1) -> mode GEMM over CI -> inv(d1,d2) -> inv(d3)+irfft(d4)
// ws: two ping-pong regions of 65536*288 float2 = 151 MB each (302 MB total).

#define K24 24   // truncated mode count dims 1..3
#define K4  12   // truncated mode count dim 4
#define NK34 288 // K24*K4
#define TWO_PI 6.28318530717958647692f

__device__ __forceinline__ void make_tw(float* twc, float* tws, int t) {
    if (t < 32) {
        float s, c;
        sincosf(TWO_PI * (float)t / 32.0f, &s, &c);
        twc[t] = c; tws[t] = s;
    }
}

// ---------------- kA: forward DFT along d4 (rfft, 12 modes) + d3 (24 modes) ----------------
// grid: 65536 = (b*32+ci)*1024 + a1*32 + a2 ; block 128
__global__ void kA(const float* __restrict__ x, float2* __restrict__ out) {
    __shared__ float xs[1024];
    __shared__ float2 T[32][12];           // [a3][k4]
    __shared__ float twc[32], tws[32];
    int t = threadIdx.x;
    make_tw(twc, tws, t);
    const float* px = x + (size_t)blockIdx.x * 1024;
    for (int i = t; i < 1024; i += 128) xs[i] = px[i];
    __syncthreads();
    // T[a3][k4] = sum_a4 xs[a3][a4] * e^{-2pi i a4 k4/32}
    for (int e = t; e < 32 * 12; e += 128) {
        int a3 = e / 12, k4 = e % 12;
        const float* row = &xs[a3 * 32];
        float sr = 0.f, si = 0.f;
#pragma unroll
        for (int a4 = 0; a4 < 32; ++a4) {
            int idx = (a4 * k4) & 31;
            float v = row[a4];
            sr += v * twc[idx];
            si -= v * tws[idx];
        }
        T[a3][k4] = make_float2(sr, si);
    }
    __syncthreads();
    // Y[k3i][k4] = sum_a3 T[a3][k4] * e^{-2pi i a3 k3/32},  k3 = k3i<12?k3i:k3i+8
    float2* po = out + (size_t)blockIdx.x * NK34;
    for (int e = t; e < NK34; e += 128) {
        int k3i = e / 12, k4 = e % 12;
        int k3 = (k3i < 12) ? k3i : k3i + 8;
        float sr = 0.f, si = 0.f;
#pragma unroll
        for (int a3 = 0; a3 < 32; ++a3) {
            int idx = (a3 * k3) & 31;
            float c = twc[idx], s = -tws[idx];
            float2 v = T[a3][k4];
            sr += v.x * c - v.y * s;
            si += v.x * s + v.y * c;
        }
        po[e] = make_float2(sr, si);
    }
}

// ---------------- kB: forward DFT along d2 then d1 (24 modes each) ----------------
// grid: 18432 = (b*32+ci)*288 + (k3i*12+k4) ; block 256
// in layout:  [bci][a1][a2][k3i][k4]   out layout: [bci][k1i][k2i][k3i][k4]
__global__ void kB(const float2* __restrict__ in, float2* __restrict__ out) {
    __shared__ float2 Xs[1024];            // [a1][a2]
    __shared__ float2 U[32][24];           // [a1][k2i]
    __shared__ float twc[32], tws[32];
    int t = threadIdx.x;
    make_tw(twc, tws, t);
    int bci = blockIdx.x / NK34;
    int rem = blockIdx.x % NK34;
    const float2* pin = in + (size_t)bci * 1024 * NK34 + rem;
    for (int i = t; i < 1024; i += 256) Xs[i] = pin[(size_t)i * NK34];
    __syncthreads();
    for (int e = t; e < 32 * 24; e += 256) {
        int a1 = e / 24, k2i = e % 24;
        int k2 = (k2i < 12) ? k2i : k2i + 8;
        float sr = 0.f, si = 0.f;
#pragma unroll
        for (int a2 = 0; a2 < 32; ++a2) {
            int idx = (a2 * k2) & 31;
            float c = twc[idx], s = -tws[idx];
            float2 v = Xs[a1 * 32 + a2];
            sr += v.x * c - v.y * s;
            si += v.x * s + v.y * c;
        }
        U[a1][k2i] = make_float2(sr, si);
    }
    __syncthreads();
    float2* pout = out + (size_t)bci * 576 * NK34 + rem;
    for (int e = t; e < 576; e += 256) {
        int k1i = e / 24;
        int k2i = e % 24;
        int k1 = (k1i < 12) ? k1i : k1i + 8;
        float sr = 0.f, si = 0.f;
#pragma unroll
        for (int a1 = 0; a1 < 32; ++a1) {
            int idx = (a1 * k1) & 31;
            float c = twc[idx], s = -tws[idx];
            float2 v = U[a1][k2i];
            sr += v.x * c - v.y * s;
            si += v.x * s + v.y * c;
        }
        pout[(size_t)e * NK34] = make_float2(sr, si);
    }
}

// ---------------- kC: per-mode complex GEMM over CI ----------------
// grid: 13824 = ((corner*12 + m1)*12 + m2)*12 + m3 ; block 384 (= 32 co * 12 k4)
// X layout: [bci][k1i][k2i][k3i][k4], W: float2 [8][32][32][20736], out: [b*32+co][k1i][k2i][k3i][k4]
__global__ void kC(const float2* __restrict__ X, const float2* __restrict__ W,
                   float2* __restrict__ out) {
    __shared__ float2 Xs[768];             // [b*32+ci][k4]
    int t = threadIdx.x;
    int m3 = blockIdx.x % 12;
    int m2 = (blockIdx.x / 12) % 12;
    int m1 = (blockIdx.x / 144) % 12;
    int corner = blockIdx.x / 1728;
    // SIGNS order: (0,0,0),(1,0,0),(0,1,0),(0,0,1),(1,1,0),(1,0,1),(0,1,1),(1,1,1)
    const int S1[8] = {0,1,0,0,1,1,0,1};
    const int S2[8] = {0,0,1,0,1,0,1,1};
    const int S3[8] = {0,0,0,1,0,1,1,1};
    int k1i = m1 + 12 * S1[corner];
    int k2i = m2 + 12 * S2[corner];
    int k3i = m3 + 12 * S3[corner];
    for (int i = t; i < 768; i += 384) {
        int bci = i / 12, k4 = i % 12;
        Xs[i] = X[(size_t)(bci * 576 + k1i * 24 + k2i) * NK34 + k3i * 12 + k4];
    }
    __syncthreads();
    int co = t / 12, k4 = t % 12;
    float2 acc0 = make_float2(0.f, 0.f), acc1 = make_float2(0.f, 0.f);
    int mlin = ((m1 * 12 + m2) * 12 + m3) * 12 + k4;
    const float2* wp = W + ((size_t)corner * 1024 + co) * 20736 + mlin;
#pragma unroll 4
    for (int ci = 0; ci < 32; ++ci) {
        float2 w = wp[(size_t)ci * 32 * 20736];
        float2 x0 = Xs[ci * 12 + k4];
        float2 x1 = Xs[384 + ci * 12 + k4];
        acc0.x += x0.x * w.x - x0.y * w.y;
        acc0.y += x0.x * w.y + x0.y * w.x;
        acc1.x += x1.x * w.x - x1.y * w.y;
        acc1.y += x1.x * w.y + x1.y * w.x;
    }
    size_t ob = (size_t)(co * 576 + k1i * 24 + k2i) * NK34 + k3i * 12 + k4;
    out[ob] = acc0;
    out[(size_t)32 * 576 * NK34 + ob] = acc1;
}

// ---------------- kD: inverse DFT along d1 then d2 (32 outputs each), x 1/1024 ----------------
// grid: 18432 = (b*32+co)*288 + (k3i*12+k4) ; block 256
// in: [bco][k1i][k2i][k3i][k4]  out: [bco][a1][a2][k3i][k4]
__global__ void kD(const float2* __restrict__ in, float2* __restrict__ out) {
    __shared__ float2 Vs[576];             // [k1i][k2i]
    __shared__ float2 U[32][24];           // [a1][k2i]
    __shared__ float twc[32], tws[32];
    int t = threadIdx.x;
    make_tw(twc, tws, t);
    int bco = blockIdx.x / NK34;
    int rem = blockIdx.x % NK34;
    const float2* pin = in + (size_t)bco * 576 * NK34 + rem;
    for (int e = t; e < 576; e += 256) Vs[e] = pin[(size_t)e * NK34];
    __syncthreads();
    for (int e = t; e < 32 * 24; e += 256) {
        int a1 = e / 24, k2i = e % 24;
        float sr = 0.f, si = 0.f;
#pragma unroll
        for (int k1i = 0; k1i < 24; ++k1i) {
            int k1 = (k1i < 12) ? k1i : k1i + 8;
            int idx = (k1 * a1) & 31;
            float c = twc[idx], s = tws[idx];   // e^{+i theta}
            float2 v = Vs[k1i * 24 + k2i];
            sr += v.x * c - v.y * s;
            si += v.x * s + v.y * c;
        }
        U[a1][k2i] = make_float2(sr, si);
    }
    __syncthreads();
    const float inv = 1.0f / 1024.0f;
    float2* pout = out + (size_t)bco * 1024 * NK34 + rem;
    for (int e = t; e < 1024; e += 256) {
        int a1 = e >> 5, a2 = e & 31;
        float sr = 0.f, si = 0.f;
#pragma unroll
        for (int k2i = 0; k2i < 24; ++k2i) {
            int k2 = (k2i < 12) ? k2i : k2i + 8;
            int idx = (k2 * a2) & 31;
            float c = twc[idx], s = tws[idx];
            float2 v = U[a1][k2i];
            sr += v.x * c - v.y * s;
            si += v.x * s + v.y * c;
        }
        pout[(size_t)e * NK34] = make_float2(sr * inv, si * inv);
    }
}

// ---------------- kE: inverse DFT along d3 + irfft along d4, x 1/1024 ----------------
// grid: 65536 = (b*32+co)*1024 + a1*32 + a2 ; block 128
// in: [bco][a1][a2][k3i][k4] (288 contiguous) -> out real [bco][a1][a2][a3][a4]
__global__ void kE(const float2* __restrict__ in, float* __restrict__ out) {
    __shared__ float2 Vs[NK34];            // [k3i][k4]
    __shared__ float2 T[32][12];           // [a3][k4]
    __shared__ float twc[32], tws[32];
    int t = threadIdx.x;
    make_tw(twc, tws, t);
    const float2* pin = in + (size_t)blockIdx.x * NK34;
    for (int i = t; i < NK34; i += 128) Vs[i] = pin[i];
    __syncthreads();
    for (int e = t; e < 32 * 12; e += 128) {
        int a3 = e / 12, k4 = e % 12;
        float sr = 0.f, si = 0.f;
#pragma unroll
        for (int k3i = 0; k3i < 24; ++k3i) {
            int k3 = (k3i < 12) ? k3i : k3i + 8;
            int idx = (k3 * a3) & 31;
            float c = twc[idx], s = tws[idx];
            float2 v = Vs[k3i * 12 + k4];
            sr += v.x * c - v.y * s;
            si += v.x * s + v.y * c;
        }
        T[a3][k4] = make_float2(sr, si);
    }
    __syncthreads();
    const float inv = 1.0f / 1024.0f;
    float* po = out + (size_t)blockIdx.x * 1024;
    for (int e = t; e < 1024; e += 128) {
        int a3 = e >> 5, a4 = e & 31;
        float acc = T[a3][0].x;             // DC: Im ignored (pocketfft irfft convention)
#pragma unroll
        for (int k4 = 1; k4 < 12; ++k4) {
            int idx = (k4 * a4) & 31;
            float2 v = T[a3][k4];
            acc += 2.0f * (v.x * twc[idx] - v.y * tws[idx]);
        }
        po[e] = acc * inv;
    }
}

extern "C" void kernel_launch(void* const* d_in, const int* in_sizes, int n_in,
                              void* d_out, int out_size, void* d_ws, size_t ws_size,
                              hipStream_t stream) {
    const float* x = (const float*)d_in[0];
    const float2* w = (const float2*)d_in[1];
    float* out = (float*)d_out;
    // two ping-pong regions of 65536*288 float2 = 150,994,944 B each (302 MB total)
    float2* r1 = (float2*)d_ws;
    float2* r2 = r1 + (size_t)65536 * NK34;

    kA<<<65536, 128, 0, stream>>>(x, r1);       // x -> Xhat(d3,d4)     [R1]
    kB<<<18432, 256, 0, stream>>>(r1, r2);      // -> Xhat(all dims)    [R2]
    kC<<<13824, 384, 0, stream>>>(r2, w, r1);   // mode GEMM over CI    [R1]
    kD<<<18432, 256, 0, stream>>>(r1, r2);      // inv d1,d2            [R2]
    kE<<<65536, 128, 0, stream>>>(r2, out);     // inv d3 + irfft d4    [out]
}